// Round 11
// baseline (135.574 us; speedup 1.0000x reference)
//
#include <hip/hip_runtime.h>
#include <hip/hip_bf16.h>
#include <math.h>

// SetConvEncoder via separable Gaussian + split-bf16 MFMA.
//  out[b][ch][gy][gx] = sum_n EX[n][gx]*EY[n][gy]*y4[n][ch]
//  = GEMM C[m=4*gy+ch][gx] += sum_k A[k][m]*B[k][n],  A=YT=EY*y4, B=EX
// History: R3 scalar main=45us (measured). R7/R8 (exp2f = OCML libcall) total
//  89-91.5us => main ~31us inferred vs ~7us pipe model. Leading theory: exp2f
//  lowers to a ~20-40-inst guarded OCML sequence, tripling staging VALU ->
//  fixed here via __builtin_amdgcn_exp2f (raw v_exp_f32).
// R11 = quad-launch measurement (R9/R10 never ran, infra):
//  T = 60.5 + 4*M.  T~85-97 => M~6-9 (exp fix worked; drop dups next round,
//  single-launch ~68us). T~175-190 => M~31 persists (next: REP-amplified probe
//  kernel to force main into top-5 with counters).
// Also: prefetch AFTER barrier (B) so its vmcnt(0) drain lands at next chunk's
//  barrier (A), hidden under frag-reads+MFMA; grid-coord hoists in registers.
// k-slot layout: A and B panels use the SAME bijective (lane-group,j)->k map ->
//  HW k-permutations cancel; load-bearing: row/col=lane&15 symmetry + m89 C/D map.

typedef float f32x4 __attribute__((ext_vector_type(4)));
typedef short s16x8 __attribute__((ext_vector_type(8)));

constexpr int BB = 8, NN = 2048, GH = 128, GW = 128;
constexpr int GY_TILE = 16;              // block covers 16 gy -> M = 64 rows
constexpr int OUTSZ = BB * 4 * GH * GW;  // 524288 floats per partial slice

__device__ __forceinline__ float fast_exp2(float x) {
    return __builtin_amdgcn_exp2f(x);    // raw v_exp_f32, ~1 ulp
}

// split v into bf16 hi + bf16 lo (lo = bf16(v - float(hi))); pack two k-adjacent
// values into one u32 per panel (low u16 = k0).
__device__ __forceinline__ void split2(float v0, float v1,
                                       unsigned& hi, unsigned& lo) {
    __hip_bfloat16 a = __float2bfloat16(v0);
    __hip_bfloat16 b = __float2bfloat16(v1);
    float fa = __bfloat162float(a), fb = __bfloat162float(b);
    __hip_bfloat16 ra = __float2bfloat16(v0 - fa);
    __hip_bfloat16 rb = __float2bfloat16(v1 - fb);
    unsigned short ua, ub, uc, ud;
    __builtin_memcpy(&ua, &a, 2);  __builtin_memcpy(&ub, &b, 2);
    __builtin_memcpy(&uc, &ra, 2); __builtin_memcpy(&ud, &rb, 2);
    hi = (unsigned)ua | ((unsigned)ub << 16);
    lo = (unsigned)uc | ((unsigned)ud << 16);
}

template <int KS, bool ATOMIC>
__global__ __launch_bounds__(256, 4) void setconv_mfma(
    const float* __restrict__ xc,    // [B,N,2]
    const float* __restrict__ yc,    // [B,N,3]
    const float* __restrict__ mask,  // [B,N]
    const float* __restrict__ logls, // [1]
    const float* __restrict__ grid,  // [H,W,2]
    float* __restrict__ dst)         // ATOMIC: out (zeroed); else partials [KS][OUTSZ]
{
    constexpr int NK  = NN / KS;     // ctx points per block
    constexpr int NCH = NK / 32;     // K-chunks of 32

    // frag-order panels: u32 slot s -> lane-row q=s>>2 (tile=q>>6, lane=q&63),
    // jp=s&3 (bf16 elems 2jp,2jp+1). One lane-row = 4 u32 = 16B = one s16x8 frag.
    __shared__ unsigned sA[2][4 * 64 * 4];   // [hi/lo][M=64 x K=32]  4 KB each
    __shared__ unsigned sB[2][8 * 64 * 4];   // [hi/lo][N=128 x K=32] 8 KB each

    const int ks  = blockIdx.x;
    const int gyt = blockIdx.y;
    const int b   = blockIdx.z;
    const int tid = threadIdx.x;
    const int l   = tid & 63;   // lane
    const int w   = tid >> 6;   // wave 0..3

    const float ls = __expf(logls[0]);
    const float cc = -0.72134752044f / (ls * ls);  // -0.5*log2(e)/ls^2

    // ---- staging decode (thread-constant) ----
    const int lane_s = tid >> 2;
    const int jp     = tid & 3;
    const int sb15   = lane_s & 15;            // n%16 (B) or m%16 (A)
    const int kg     = lane_s >> 4;            // k-group 0..3
    const int k0     = ((jp >> 1) << 4) | (kg << 2) | ((jp & 1) << 1); // even
    const int ch     = sb15 & 3;               // A: channel
    const int gyb    = sb15 >> 2;              // A: gy%4 base

    // hoisted grid coordinates (loop-invariant, static-indexed -> registers)
    float gxv[8];
#pragma unroll
    for (int r = 0; r < 8; ++r) gxv[r] = grid[(r * 16 + sb15) * 2 + 0];
    float gyv[4];
#pragma unroll
    for (int r = 0; r < 4; ++r)
        gyv[r] = grid[(size_t)(gyt * GY_TILE + r * 4 + gyb) * GW * 2 + 1];

    // wave tile: 2 m-tiles x 4 n-tiles of 16x16
    const int mtb = (w & 1) * 2;
    const int ntb = (w >> 1) * 4;

    f32x4 acc[2][4];
#pragma unroll
    for (int i = 0; i < 2; ++i)
#pragma unroll
        for (int j = 0; j < 4; ++j) acc[i][j] = (f32x4){0.f, 0.f, 0.f, 0.f};

    const int nb0 = b * NN + ks * NK;

    // ---- prefetch chunk 0 globals into registers ----
    int kb = nb0 + k0;
    float4 xy = *(const float4*)&xc[(size_t)kb * 2];  // x0,y0,x1,y1 (k0 even)
    float2 mk = *(const float2*)&mask[kb];
    float yv0 = 0.f, yv1 = 0.f;
    if (ch < 3) {
        yv0 = yc[(size_t)kb * 3 + ch];
        yv1 = yc[(size_t)(kb + 1) * 3 + ch];
    }

    for (int chn = 0; chn < NCH; ++chn) {
        __syncthreads();  // (A) previous chunk's frag reads done; prefetch drains

        const float y40 = (ch < 3) ? yv0 * mk.x : mk.x;
        const float y41 = (ch < 3) ? yv1 * mk.y : mk.y;

        // ---- stage B = EX (8 n-tiles): conflict-free consecutive-u32 writes ----
#pragma unroll
        for (int r = 0; r < 8; ++r) {
            float d0 = gxv[r] - xy.x, d1 = gxv[r] - xy.z;
            unsigned hi, lo;
            split2(fast_exp2(cc * d0 * d0), fast_exp2(cc * d1 * d1), hi, lo);
            sB[0][r * 256 + tid] = hi;
            sB[1][r * 256 + tid] = lo;
        }
        // ---- stage A = YT (4 m-tiles) ----
#pragma unroll
        for (int r = 0; r < 4; ++r) {
            float d0 = gyv[r] - xy.y, d1 = gyv[r] - xy.w;
            unsigned hi, lo;
            split2(fast_exp2(cc * d0 * d0) * y40,
                   fast_exp2(cc * d1 * d1) * y41, hi, lo);
            sA[0][r * 256 + tid] = hi;
            sA[1][r * 256 + tid] = lo;
        }
        __syncthreads();  // (B) panels visible

        // ---- prefetch next chunk AFTER barrier: overlaps frag-reads+MFMA,
        //      drains at next (A) -- not exposed
        if (chn + 1 < NCH) {
            kb = nb0 + (chn + 1) * 32 + k0;
            xy = *(const float4*)&xc[(size_t)kb * 2];
            mk = *(const float2*)&mask[kb];
            if (ch < 3) {
                yv0 = yc[(size_t)kb * 3 + ch];
                yv1 = yc[(size_t)(kb + 1) * 3 + ch];
            }
        }

        // ---- fragments + 24 MFMAs (B frags per-j to cut live VGPRs) ----
        const s16x8* pAh = (const s16x8*)sA[0];
        const s16x8* pAl = (const s16x8*)sA[1];
        const s16x8* pBh = (const s16x8*)sB[0];
        const s16x8* pBl = (const s16x8*)sB[1];
        s16x8 ah[2], al[2];
#pragma unroll
        for (int i = 0; i < 2; ++i) {
            ah[i] = pAh[(mtb + i) * 64 + l];
            al[i] = pAl[(mtb + i) * 64 + l];
        }
#pragma unroll
        for (int j = 0; j < 4; ++j) {
            s16x8 bh = pBh[(ntb + j) * 64 + l];
            s16x8 bl = pBl[(ntb + j) * 64 + l];
#pragma unroll
            for (int i = 0; i < 2; ++i) {
                acc[i][j] = __builtin_amdgcn_mfma_f32_16x16x32_bf16(
                    ah[i], bh, acc[i][j], 0, 0, 0);
                acc[i][j] = __builtin_amdgcn_mfma_f32_16x16x32_bf16(
                    ah[i], bl, acc[i][j], 0, 0, 0);
                acc[i][j] = __builtin_amdgcn_mfma_f32_16x16x32_bf16(
                    al[i], bh, acc[i][j], 0, 0, 0);
            }
        }
    }

    // ---- epilogue: C/D map col=l&15 (gx), row=(l>>4)*4+reg (m=4*gy+ch) ----
    const int colg = l & 15, rowg = l >> 4;
    float* slice = ATOMIC ? dst : dst + (size_t)ks * OUTSZ;
#pragma unroll
    for (int i = 0; i < 2; ++i) {
        const int gy = gyt * GY_TILE + (mtb + i) * 4 + rowg;
#pragma unroll
        for (int j = 0; j < 4; ++j) {
            const int gx = (ntb + j) * 16 + colg;
#pragma unroll
            for (int r = 0; r < 4; ++r) {  // r == channel
                const size_t off = (((size_t)(b * 4 + r)) * GH + gy) * GW + gx;
                if (ATOMIC) atomicAdd(&slice[off], acc[i][j][r]);
                else        slice[off] = acc[i][j][r];
            }
        }
    }
}

template <int KS>
__global__ __launch_bounds__(256, 8) void setconv_reduce(
    const float* __restrict__ pw,  // [KS][OUTSZ]
    float* __restrict__ out)       // [OUTSZ]
{
    const int n4 = OUTSZ / 4;
    const int stride = gridDim.x * 256;
    const float4* p = (const float4*)pw;
    for (int i = blockIdx.x * 256 + threadIdx.x; i < n4; i += stride) {
        float4 s = p[i];
#pragma unroll
        for (int k = 1; k < KS; ++k) {
            float4 v = p[(size_t)k * n4 + i];
            s.x += v.x; s.y += v.y; s.z += v.z; s.w += v.w;
        }
        ((float4*)out)[i] = s;
    }
}

extern "C" void kernel_launch(void* const* d_in, const int* in_sizes, int n_in,
                              void* d_out, int out_size, void* d_ws, size_t ws_size,
                              hipStream_t stream) {
    const float* xc    = (const float*)d_in[0];  // x_context [8,2048,2]
    const float* yc    = (const float*)d_in[1];  // y_context [8,2048,3]
    const float* mask  = (const float*)d_in[2];  // context_mask [8,2048]
    const float* logls = (const float*)d_in[3];  // log_lengthscale [1]
    const float* grid  = (const float*)d_in[4];  // grid [128,128,2]
    float* out = (float*)d_out;                  // [8,4,128,128]

    const size_t slice_set = (size_t)16 * OUTSZ;              // 32 MB in floats
    const size_t need1 = slice_set * sizeof(float);           //  32 MB
    const size_t need4 = 4 * need1;                           // 128 MB (quad)
    dim3 gdim(16, GH / GY_TILE, BB);  // 1024 blocks

    if (ws_size >= need4) {
        // MEASUREMENT: main launched 4x into disjoint slice-sets; sets 1-3
        // discarded. M = (T - 60.5us)/4 per R8 calibration.
        float* pw = (float*)d_ws;
        for (int rep = 0; rep < 4; ++rep)
            setconv_mfma<16, false><<<gdim, 256, 0, stream>>>(
                xc, yc, mask, logls, grid, pw + rep * slice_set);
        setconv_reduce<16><<<dim3(512), 256, 0, stream>>>(pw, out);
    } else if (ws_size >= need1) {
        float* pw = (float*)d_ws;
        setconv_mfma<16, false><<<gdim, 256, 0, stream>>>(xc, yc, mask, logls,
                                                          grid, pw);
        setconv_reduce<16><<<dim3(512), 256, 0, stream>>>(pw, out);
    } else {
        hipMemsetAsync(out, 0, (size_t)out_size * sizeof(float), stream);
        dim3 gdim8(8, GH / GY_TILE, BB);
        setconv_mfma<8, true><<<gdim8, 256, 0, stream>>>(xc, yc, mask, logls,
                                                         grid, out);
    }
}

// Round 12
// 89.412 us; speedup vs baseline: 1.5163x; 1.5163x over previous
//
#include <hip/hip_runtime.h>
#include <hip/hip_bf16.h>
#include <math.h>

// SetConvEncoder via separable Gaussian + split-bf16 MFMA.
//  out[b][ch][gy][gx] = sum_n EX[n][gx]*EY[n][gy]*y4[n][ch]
//  = GEMM C[m=4*gy+ch][gx] += sum_k A[k][m]*B[k][n],  A=YT=EY*y4, B=EX
// History: R3 scalar main=45us. R7/R8 (OCML exp2f): total 89-91.5us.
//  R11 quad-launch measurement: T=135.6 => M+gap ~= 14.7us per main launch
//  (M ~15-18us) -- R8's "31us main" inference overstated (per-dispatch gaps
//  bigger than credited). Harness floor: ~40us ws-poison fill + out-fill +
//  input restores + gaps ~= 55us/iteration, irreducible from kernel side.
// R12: kernel byte-identical to R11; launcher drops the 3 duplicate launches.
//  Completes the 2-equation solve: T11-T12 = 3(M+gap); T12-T8 = M_fix - M_ocml.
//  Predicted total ~77-81us.
// Kernel contains: __builtin_amdgcn_exp2f (raw v_exp_f32); prefetch AFTER
//  barrier (B) (vmcnt(0) drain lands at next chunk's (A), hidden under MFMA);
//  grid-coord hoists; KS16 -> 1024 blocks, 4 blocks/CU.
// k-slot layout: A and B panels use the SAME bijective (lane-group,j)->k map ->
//  HW k-permutations cancel; load-bearing: row/col=lane&15 symmetry + m89 C/D map.

typedef float f32x4 __attribute__((ext_vector_type(4)));
typedef short s16x8 __attribute__((ext_vector_type(8)));

constexpr int BB = 8, NN = 2048, GH = 128, GW = 128;
constexpr int GY_TILE = 16;              // block covers 16 gy -> M = 64 rows
constexpr int OUTSZ = BB * 4 * GH * GW;  // 524288 floats per partial slice

__device__ __forceinline__ float fast_exp2(float x) {
    return __builtin_amdgcn_exp2f(x);    // raw v_exp_f32, ~1 ulp
}

// split v into bf16 hi + bf16 lo (lo = bf16(v - float(hi))); pack two k-adjacent
// values into one u32 per panel (low u16 = k0).
__device__ __forceinline__ void split2(float v0, float v1,
                                       unsigned& hi, unsigned& lo) {
    __hip_bfloat16 a = __float2bfloat16(v0);
    __hip_bfloat16 b = __float2bfloat16(v1);
    float fa = __bfloat162float(a), fb = __bfloat162float(b);
    __hip_bfloat16 ra = __float2bfloat16(v0 - fa);
    __hip_bfloat16 rb = __float2bfloat16(v1 - fb);
    unsigned short ua, ub, uc, ud;
    __builtin_memcpy(&ua, &a, 2);  __builtin_memcpy(&ub, &b, 2);
    __builtin_memcpy(&uc, &ra, 2); __builtin_memcpy(&ud, &rb, 2);
    hi = (unsigned)ua | ((unsigned)ub << 16);
    lo = (unsigned)uc | ((unsigned)ud << 16);
}

template <int KS, bool ATOMIC>
__global__ __launch_bounds__(256, 4) void setconv_mfma(
    const float* __restrict__ xc,    // [B,N,2]
    const float* __restrict__ yc,    // [B,N,3]
    const float* __restrict__ mask,  // [B,N]
    const float* __restrict__ logls, // [1]
    const float* __restrict__ grid,  // [H,W,2]
    float* __restrict__ dst)         // ATOMIC: out (zeroed); else partials [KS][OUTSZ]
{
    constexpr int NK  = NN / KS;     // ctx points per block
    constexpr int NCH = NK / 32;     // K-chunks of 32

    // frag-order panels: u32 slot s -> lane-row q=s>>2 (tile=q>>6, lane=q&63),
    // jp=s&3 (bf16 elems 2jp,2jp+1). One lane-row = 4 u32 = 16B = one s16x8 frag.
    __shared__ unsigned sA[2][4 * 64 * 4];   // [hi/lo][M=64 x K=32]  4 KB each
    __shared__ unsigned sB[2][8 * 64 * 4];   // [hi/lo][N=128 x K=32] 8 KB each

    const int ks  = blockIdx.x;
    const int gyt = blockIdx.y;
    const int b   = blockIdx.z;
    const int tid = threadIdx.x;
    const int l   = tid & 63;   // lane
    const int w   = tid >> 6;   // wave 0..3

    const float ls = __expf(logls[0]);
    const float cc = -0.72134752044f / (ls * ls);  // -0.5*log2(e)/ls^2

    // ---- staging decode (thread-constant) ----
    const int lane_s = tid >> 2;
    const int jp     = tid & 3;
    const int sb15   = lane_s & 15;            // n%16 (B) or m%16 (A)
    const int kg     = lane_s >> 4;            // k-group 0..3
    const int k0     = ((jp >> 1) << 4) | (kg << 2) | ((jp & 1) << 1); // even
    const int ch     = sb15 & 3;               // A: channel
    const int gyb    = sb15 >> 2;              // A: gy%4 base

    // hoisted grid coordinates (loop-invariant, static-indexed -> registers)
    float gxv[8];
#pragma unroll
    for (int r = 0; r < 8; ++r) gxv[r] = grid[(r * 16 + sb15) * 2 + 0];
    float gyv[4];
#pragma unroll
    for (int r = 0; r < 4; ++r)
        gyv[r] = grid[(size_t)(gyt * GY_TILE + r * 4 + gyb) * GW * 2 + 1];

    // wave tile: 2 m-tiles x 4 n-tiles of 16x16
    const int mtb = (w & 1) * 2;
    const int ntb = (w >> 1) * 4;

    f32x4 acc[2][4];
#pragma unroll
    for (int i = 0; i < 2; ++i)
#pragma unroll
        for (int j = 0; j < 4; ++j) acc[i][j] = (f32x4){0.f, 0.f, 0.f, 0.f};

    const int nb0 = b * NN + ks * NK;

    // ---- prefetch chunk 0 globals into registers ----
    int kb = nb0 + k0;
    float4 xy = *(const float4*)&xc[(size_t)kb * 2];  // x0,y0,x1,y1 (k0 even)
    float2 mk = *(const float2*)&mask[kb];
    float yv0 = 0.f, yv1 = 0.f;
    if (ch < 3) {
        yv0 = yc[(size_t)kb * 3 + ch];
        yv1 = yc[(size_t)(kb + 1) * 3 + ch];
    }

    for (int chn = 0; chn < NCH; ++chn) {
        __syncthreads();  // (A) previous chunk's frag reads done; prefetch drains

        const float y40 = (ch < 3) ? yv0 * mk.x : mk.x;
        const float y41 = (ch < 3) ? yv1 * mk.y : mk.y;

        // ---- stage B = EX (8 n-tiles): conflict-free consecutive-u32 writes ----
#pragma unroll
        for (int r = 0; r < 8; ++r) {
            float d0 = gxv[r] - xy.x, d1 = gxv[r] - xy.z;
            unsigned hi, lo;
            split2(fast_exp2(cc * d0 * d0), fast_exp2(cc * d1 * d1), hi, lo);
            sB[0][r * 256 + tid] = hi;
            sB[1][r * 256 + tid] = lo;
        }
        // ---- stage A = YT (4 m-tiles) ----
#pragma unroll
        for (int r = 0; r < 4; ++r) {
            float d0 = gyv[r] - xy.y, d1 = gyv[r] - xy.w;
            unsigned hi, lo;
            split2(fast_exp2(cc * d0 * d0) * y40,
                   fast_exp2(cc * d1 * d1) * y41, hi, lo);
            sA[0][r * 256 + tid] = hi;
            sA[1][r * 256 + tid] = lo;
        }
        __syncthreads();  // (B) panels visible

        // ---- prefetch next chunk AFTER barrier: overlaps frag-reads+MFMA,
        //      drains at next (A) -- not exposed
        if (chn + 1 < NCH) {
            kb = nb0 + (chn + 1) * 32 + k0;
            xy = *(const float4*)&xc[(size_t)kb * 2];
            mk = *(const float2*)&mask[kb];
            if (ch < 3) {
                yv0 = yc[(size_t)kb * 3 + ch];
                yv1 = yc[(size_t)(kb + 1) * 3 + ch];
            }
        }

        // ---- fragments + 24 MFMAs (B frags per-j to cut live VGPRs) ----
        const s16x8* pAh = (const s16x8*)sA[0];
        const s16x8* pAl = (const s16x8*)sA[1];
        const s16x8* pBh = (const s16x8*)sB[0];
        const s16x8* pBl = (const s16x8*)sB[1];
        s16x8 ah[2], al[2];
#pragma unroll
        for (int i = 0; i < 2; ++i) {
            ah[i] = pAh[(mtb + i) * 64 + l];
            al[i] = pAl[(mtb + i) * 64 + l];
        }
#pragma unroll
        for (int j = 0; j < 4; ++j) {
            s16x8 bh = pBh[(ntb + j) * 64 + l];
            s16x8 bl = pBl[(ntb + j) * 64 + l];
#pragma unroll
            for (int i = 0; i < 2; ++i) {
                acc[i][j] = __builtin_amdgcn_mfma_f32_16x16x32_bf16(
                    ah[i], bh, acc[i][j], 0, 0, 0);
                acc[i][j] = __builtin_amdgcn_mfma_f32_16x16x32_bf16(
                    ah[i], bl, acc[i][j], 0, 0, 0);
                acc[i][j] = __builtin_amdgcn_mfma_f32_16x16x32_bf16(
                    al[i], bh, acc[i][j], 0, 0, 0);
            }
        }
    }

    // ---- epilogue: C/D map col=l&15 (gx), row=(l>>4)*4+reg (m=4*gy+ch) ----
    const int colg = l & 15, rowg = l >> 4;
    float* slice = ATOMIC ? dst : dst + (size_t)ks * OUTSZ;
#pragma unroll
    for (int i = 0; i < 2; ++i) {
        const int gy = gyt * GY_TILE + (mtb + i) * 4 + rowg;
#pragma unroll
        for (int j = 0; j < 4; ++j) {
            const int gx = (ntb + j) * 16 + colg;
#pragma unroll
            for (int r = 0; r < 4; ++r) {  // r == channel
                const size_t off = (((size_t)(b * 4 + r)) * GH + gy) * GW + gx;
                if (ATOMIC) atomicAdd(&slice[off], acc[i][j][r]);
                else        slice[off] = acc[i][j][r];
            }
        }
    }
}

template <int KS>
__global__ __launch_bounds__(256, 8) void setconv_reduce(
    const float* __restrict__ pw,  // [KS][OUTSZ]
    float* __restrict__ out)       // [OUTSZ]
{
    const int n4 = OUTSZ / 4;
    const int stride = gridDim.x * 256;
    const float4* p = (const float4*)pw;
    for (int i = blockIdx.x * 256 + threadIdx.x; i < n4; i += stride) {
        float4 s = p[i];
#pragma unroll
        for (int k = 1; k < KS; ++k) {
            float4 v = p[(size_t)k * n4 + i];
            s.x += v.x; s.y += v.y; s.z += v.z; s.w += v.w;
        }
        ((float4*)out)[i] = s;
    }
}

extern "C" void kernel_launch(void* const* d_in, const int* in_sizes, int n_in,
                              void* d_out, int out_size, void* d_ws, size_t ws_size,
                              hipStream_t stream) {
    const float* xc    = (const float*)d_in[0];  // x_context [8,2048,2]
    const float* yc    = (const float*)d_in[1];  // y_context [8,2048,3]
    const float* mask  = (const float*)d_in[2];  // context_mask [8,2048]
    const float* logls = (const float*)d_in[3];  // log_lengthscale [1]
    const float* grid  = (const float*)d_in[4];  // grid [128,128,2]
    float* out = (float*)d_out;                  // [8,4,128,128]

    const size_t need1 = (size_t)16 * OUTSZ * sizeof(float);  // 32 MB
    dim3 gdim(16, GH / GY_TILE, BB);  // 1024 blocks -> 4/CU

    if (ws_size >= need1) {
        float* pw = (float*)d_ws;
        setconv_mfma<16, false><<<gdim, 256, 0, stream>>>(xc, yc, mask, logls,
                                                          grid, pw);
        setconv_reduce<16><<<dim3(512), 256, 0, stream>>>(pw, out);
    } else {
        hipMemsetAsync(out, 0, (size_t)out_size * sizeof(float), stream);
        dim3 gdim8(8, GH / GY_TILE, BB);
        setconv_mfma<8, true><<<gdim8, 256, 0, stream>>>(xc, yc, mask, logls,
                                                         grid, out);
    }
}